// Round 2
// baseline (1183.611 us; speedup 1.0000x reference)
//
#include <hip/hip_runtime.h>
#include <hip/hip_bf16.h>

#define BATCH 16
#define NE 4
#define DIM 64
#define RANK 32
#define H 128
#define W 128
#define HW (H*W)

static __device__ __forceinline__ float bu2f(unsigned short u) {
    return __uint_as_float(((unsigned)u) << 16);
}
static __device__ __forceinline__ unsigned short f2bu(float f) {
    union { __hip_bfloat16 h; unsigned short u; } cv;
    cv.h = __float2bfloat16(f);
    return cv.u;
}

// ---------------- routing ----------------
__global__ __launch_bounds__(256) void k_pool(const float* __restrict__ x,
                                              float* __restrict__ pooled) {
    int bc = blockIdx.x;  // 0..1023 = b*64+c
    const float4* p = (const float4*)(x + (size_t)bc * HW);
    float s = 0.f;
    for (int i = threadIdx.x; i < HW / 4; i += 256) {
        float4 v = p[i];
        s += v.x + v.y + v.z + v.w;
    }
#pragma unroll
    for (int off = 32; off > 0; off >>= 1) s += __shfl_down(s, off);
    __shared__ float red[4];
    if ((threadIdx.x & 63) == 0) red[threadIdx.x >> 6] = s;
    __syncthreads();
    if (threadIdx.x == 0)
        pooled[bc] = (red[0] + red[1] + red[2] + red[3]) * (1.f / HW);
}

__global__ __launch_bounds__(64) void k_gate(const float* __restrict__ pooled,
                                             const float* __restrict__ freq_emb,
                                             const float* __restrict__ noise,
                                             const float* __restrict__ gate_w,
                                             const float* __restrict__ fgw,
                                             float* __restrict__ gates,
                                             float* __restrict__ gsum) {
    int b = threadIdx.x;
    if (b >= BATCH) return;
    float lg[4];
    for (int e = 0; e < 4; e++) {
        float s = 0.f;
        for (int c = 0; c < 64; c++) s += pooled[b * 64 + c] * gate_w[e * 64 + c];
        for (int c = 0; c < 64; c++) s += freq_emb[b * 64 + c] * fgw[e * 64 + c];
        s += noise[b * 4 + e] * 0.25f;  // NOISE_STD = 1/E
        lg[e] = s;
    }
    float m = fmaxf(fmaxf(lg[0], lg[1]), fmaxf(lg[2], lg[3]));
    float sc[4], Z = 0.f;
    for (int e = 0; e < 4; e++) { sc[e] = expf(lg[e] - m); Z += sc[e]; }
    for (int e = 0; e < 4; e++) sc[e] /= Z;
    int i0 = 0;
    for (int e = 1; e < 4; e++) if (sc[e] > sc[i0]) i0 = e;
    int i1 = -1;
    for (int e = 0; e < 4; e++) {
        if (e == i0) continue;
        if (i1 < 0 || sc[e] > sc[i1]) i1 = e;
    }
    float g[4] = {0.f, 0.f, 0.f, 0.f};
    g[i0] = sc[i0]; g[i1] = sc[i1];
    for (int e = 0; e < 4; e++) gates[b * 4 + e] = g[e];
    gsum[b] = sc[i0] + sc[i1];
}

// ---------------- weight prep ----------------
// weff[e][c][j] = (j<32 ? q_w[e][j][:] : kv_w[e][j-32][:]) . p0[e][:][c]
__global__ __launch_bounds__(256) void k_weff(const float* __restrict__ q_w,
                                              const float* __restrict__ kv_w,
                                              const float* __restrict__ p0,
                                              float* __restrict__ weff) {
    int t = blockIdx.x * 256 + threadIdx.x;  // e*96*64
    if (t >= NE * 96 * 64) return;
    int c = t & 63;
    int j = (t >> 6) % 96;
    int e = t / (96 * 64);
    const float* p0p = p0 + (size_t)e * RANK * DIM;
    float s = 0.f;
    if (j < 32) {
        const float* qp = q_w + (e * 32 + j) * 32;
        for (int r = 0; r < 32; r++) s += qp[r] * p0p[r * DIM + c];
    } else {
        const float* kp = kv_w + (e * 64 + (j - 32)) * 32;
        for (int r = 0; r < 32; r++) s += kp[r] * p0p[r * DIM + c];
    }
    weff[(e * 64 + c) * 96 + j] = s;
}

// transpose po_w [e][oc][c]->[e][c][oc] and p1 [e][j][c]->[e][c][j]
__global__ __launch_bounds__(256) void k_xpose(const float* __restrict__ po_w,
                                               const float* __restrict__ p1,
                                               float* __restrict__ powf,
                                               float* __restrict__ p1f) {
    int t = blockIdx.x * 256 + threadIdx.x;  // 8192
    if (t < 4096) {
        int e = t >> 10, oc = (t >> 5) & 31, c = t & 31;
        powf[(e * 32 + c) * 32 + oc] = po_w[t];
    }
    int e = t >> 11, j = (t >> 6) & 31, c = t & 63;
    p1f[(e * 64 + c) * 32 + j] = p1[t];
}

// out = gsum[b] * x  (residual term, pulled out of the per-expert sum)
__global__ __launch_bounds__(256) void k_init(const float* __restrict__ x,
                                              const float* __restrict__ gsum,
                                              float* __restrict__ out) {
    size_t i = ((size_t)blockIdx.x * 256 + threadIdx.x) * 4;
    int b = (int)(i >> 20);  // DIM*HW = 2^20
    float g = gsum[b];
    float4 v = *(const float4*)(x + i);
    v.x *= g; v.y *= g; v.z *= g; v.w *= g;
    *(float4*)(out + i) = v;
}

// ---------------- per-expert pipeline ----------------
// fused conv1x1: qkvpre[b][j][p] = sum_c weff[e][c][j] * x[b][c][p], j in [0,96)
__global__ __launch_bounds__(256) void k_qkvpre(const float* __restrict__ x,
                                                const float* __restrict__ weff,
                                                const float* __restrict__ gates, int e,
                                                unsigned short* __restrict__ qkvpre) {
    int pt = blockIdx.x & 15;          // 16 tiles of 1024 px
    int jg = (blockIdx.x >> 4) % 3;    // 3 groups of 32 out-channels
    int b = blockIdx.x / 48;
    if (gates[b * 4 + e] == 0.f) return;
    const float* wp = weff + e * 96 * 64 + jg * 32;
    int p0 = pt * 1024 + threadIdx.x * 4;  // 4 consecutive pixels / thread
    const float* xb = x + (size_t)b * DIM * HW + p0;
    float a0[32], a1[32], a2[32], a3[32];
#pragma unroll
    for (int j = 0; j < 32; j++) { a0[j] = 0.f; a1[j] = 0.f; a2[j] = 0.f; a3[j] = 0.f; }
    for (int c = 0; c < DIM; c++) {
        float4 xv = *(const float4*)(xb + (size_t)c * HW);
        const float* wr = wp + c * 96;
#pragma unroll
        for (int j = 0; j < 32; j++) {
            float wv = wr[j];
            a0[j] += wv * xv.x; a1[j] += wv * xv.y; a2[j] += wv * xv.z; a3[j] += wv * xv.w;
        }
    }
    unsigned short* op = qkvpre + ((size_t)b * 96 + jg * 32) * HW + p0;
#pragma unroll
    for (int j = 0; j < 32; j++) {
        ushort4 o4;
        o4.x = f2bu(a0[j]); o4.y = f2bu(a1[j]); o4.z = f2bu(a2[j]); o4.w = f2bu(a3[j]);
        *(ushort4*)(op + (size_t)j * HW) = o4;
    }
}

// depthwise 3x3 pad1 on channels 0..31
__global__ __launch_bounds__(256) void k_dw3(const unsigned short* __restrict__ qkvpre,
                                             const float* __restrict__ q_dw,
                                             const float* __restrict__ gates, int e,
                                             unsigned short* __restrict__ qkv) {
    int pt = blockIdx.x & 15;
    int c = (blockIdx.x >> 4) & 31;
    int b = blockIdx.x >> 9;
    if (gates[b * 4 + e] == 0.f) return;
    const float* wp = q_dw + (e * 32 + c) * 9;
    int tx = (threadIdx.x & 31) * 4;
    int ty = threadIdx.x >> 5;
    int y = pt * 8 + ty;
    const unsigned short* in = qkvpre + ((size_t)b * 96 + c) * HW;
    float s0 = 0.f, s1 = 0.f, s2 = 0.f, s3 = 0.f;
#pragma unroll
    for (int ky = 0; ky < 3; ky++) {
        int yy = y + ky - 1;
        if (yy < 0 || yy >= H) continue;
        const unsigned short* row = in + yy * W;
        float r[6];
#pragma unroll
        for (int d = 0; d < 6; d++) {
            int xx = tx + d - 1;
            r[d] = (xx >= 0 && xx < W) ? bu2f(row[xx]) : 0.f;
        }
#pragma unroll
        for (int kx = 0; kx < 3; kx++) {
            float wv = wp[ky * 3 + kx];
            s0 += wv * r[kx]; s1 += wv * r[kx + 1]; s2 += wv * r[kx + 2]; s3 += wv * r[kx + 3];
        }
    }
    ushort4 o4; o4.x = f2bu(s0); o4.y = f2bu(s1); o4.z = f2bu(s2); o4.w = f2bu(s3);
    *(ushort4*)(qkv + ((size_t)b * 96 + c) * HW + y * W + tx) = o4;
}

// depthwise 7x7 pad3 on channels 32..95
__global__ __launch_bounds__(256) void k_dw7(const unsigned short* __restrict__ qkvpre,
                                             const float* __restrict__ kv_dw,
                                             const float* __restrict__ gates, int e,
                                             unsigned short* __restrict__ qkv) {
    int pt = blockIdx.x & 15;
    int c = (blockIdx.x >> 4) & 63;
    int b = blockIdx.x >> 10;
    if (gates[b * 4 + e] == 0.f) return;
    const float* wp = kv_dw + (e * 64 + c) * 49;
    int tx = (threadIdx.x & 31) * 4;
    int ty = threadIdx.x >> 5;
    int y = pt * 8 + ty;
    const unsigned short* in = qkvpre + ((size_t)b * 96 + 32 + c) * HW;
    float s0 = 0.f, s1 = 0.f, s2 = 0.f, s3 = 0.f;
#pragma unroll
    for (int ky = 0; ky < 7; ky++) {
        int yy = y + ky - 3;
        if (yy < 0 || yy >= H) continue;
        const unsigned short* row = in + yy * W;
        float r[10];
#pragma unroll
        for (int d = 0; d < 10; d++) {
            int xx = tx + d - 3;
            r[d] = (xx >= 0 && xx < W) ? bu2f(row[xx]) : 0.f;
        }
#pragma unroll
        for (int kx = 0; kx < 7; kx++) {
            float wv = wp[ky * 7 + kx];
            s0 += wv * r[kx]; s1 += wv * r[kx + 1]; s2 += wv * r[kx + 2]; s3 += wv * r[kx + 3];
        }
    }
    ushort4 o4; o4.x = f2bu(s0); o4.y = f2bu(s1); o4.z = f2bu(s2); o4.w = f2bu(s3);
    *(ushort4*)(qkv + ((size_t)b * 96 + 32 + c) * HW + y * W + tx) = o4;
}

// per-8x8-patch circular convolution o = q (*) k  (== irfft2(rfft2(q)*rfft2(k)))
__global__ __launch_bounds__(256) void k_circ(const unsigned short* __restrict__ qkv,
                                              const float* __restrict__ gates, int e,
                                              float* __restrict__ o) {
    int b = blockIdx.x >> 11;  // 2048 blocks per image
    if (gates[b * 4 + e] == 0.f) return;
    int u4 = ((blockIdx.x & 2047) << 2) | (threadIdx.x >> 6);  // unit = (c, patch)
    int c = u4 >> 8;
    int patch = u4 & 255;
    int py = patch >> 4, px = patch & 15;
    int l = threadIdx.x & 63;
    int i = l >> 3, j = l & 7;
    size_t base = ((size_t)b * 96 + c) * HW + (py * 8 + i) * W + px * 8 + j;
    float qv = bu2f(qkv[base]);
    float kv = bu2f(qkv[base + (size_t)32 * HW]);
    float acc = 0.f;
#pragma unroll
    for (int m = 0; m < 64; m++) {
        float qm = __shfl(qv, m);
        int mi = m >> 3, mj = m & 7;
        int idx = (((i - mi) & 7) << 3) | ((j - mj) & 7);
        acc += qm * __shfl(kv, idx);
    }
    o[((size_t)b * 32 + c) * HW + (py * 8 + i) * W + px * 8 + j] = acc;
}

// fused: channel-LN -> *v -> po proj -> *silu(p1@shared) -> p2 proj -> gated accumulate
__global__ __launch_bounds__(256) void k_tail(const float* __restrict__ o,
                                              const unsigned short* __restrict__ qkv,
                                              const float* __restrict__ shr,
                                              const float* __restrict__ gates, int e,
                                              const float* __restrict__ powf,
                                              const float* __restrict__ po_b,
                                              const float* __restrict__ ln_w,
                                              const float* __restrict__ ln_b,
                                              const float* __restrict__ p1f,
                                              const float* __restrict__ p2,
                                              float* __restrict__ out) {
    int b = blockIdx.x >> 6;
    float g = gates[b * 4 + e];
    if (g == 0.f) return;
    int p = ((blockIdx.x & 63) << 8) + threadIdx.x;
    const float* op = o + (size_t)b * 32 * HW + p;
    float mu = 0.f;
    for (int c = 0; c < 32; c++) mu += op[(size_t)c * HW];
    mu *= (1.f / 32.f);
    float var = 0.f;
    for (int c = 0; c < 32; c++) { float d = op[(size_t)c * HW] - mu; var += d * d; }
    float rinv = rsqrtf(var * (1.f / 32.f) + 1e-5f);
    const float* powp = powf + e * 1024;
    const float* lnwp = ln_w + e * 32;
    const float* lnbp = ln_b + e * 32;
    const float* pobp = po_b + e * 32;
    const unsigned short* vp = qkv + ((size_t)b * 96 + 64) * HW + p;
    float att[32];
#pragma unroll
    for (int j = 0; j < 32; j++) att[j] = pobp[j];
    for (int c = 0; c < 32; c++) {
        float u = ((op[(size_t)c * HW] - mu) * rinv * lnwp[c] + lnbp[c]) * bu2f(vp[(size_t)c * HW]);
        const float* pr = powp + c * 32;
#pragma unroll
        for (int j = 0; j < 32; j++) att[j] += pr[j] * u;
    }
    float t[32];
#pragma unroll
    for (int j = 0; j < 32; j++) t[j] = 0.f;
    const float* shp = shr + (size_t)b * 64 * HW + p;
    const float* p1p = p1f + e * 2048;
    for (int c = 0; c < 64; c++) {
        float sv = shp[(size_t)c * HW];
        const float* pr = p1p + c * 32;
#pragma unroll
        for (int j = 0; j < 32; j++) t[j] += pr[j] * sv;
    }
#pragma unroll
    for (int j = 0; j < 32; j++) {
        float tv = t[j];
        att[j] *= tv * __builtin_amdgcn_rcpf(1.f + __expf(-tv));  // silu
    }
    float* oa = out + (size_t)b * 64 * HW + p;
    const float* p2p = p2 + e * 2048;
    for (int oc = 0; oc < 64; oc++) {
        const float* pr = p2p + oc * 32;
        float s = 0.f;
#pragma unroll
        for (int j = 0; j < 32; j++) s += pr[j] * att[j];
        oa[(size_t)oc * HW] += g * s;
    }
}

extern "C" void kernel_launch(void* const* d_in, const int* in_sizes, int n_in,
                              void* d_out, int out_size, void* d_ws, size_t ws_size,
                              hipStream_t stream) {
    (void)in_sizes; (void)n_in; (void)out_size; (void)ws_size;
    const float* x      = (const float*)d_in[0];
    const float* shr    = (const float*)d_in[1];
    const float* femb   = (const float*)d_in[2];
    const float* noise  = (const float*)d_in[3];
    const float* gate_w = (const float*)d_in[4];
    const float* fgw    = (const float*)d_in[5];
    const float* p0     = (const float*)d_in[6];
    const float* p1     = (const float*)d_in[7];
    const float* p2     = (const float*)d_in[8];
    const float* q_w    = (const float*)d_in[9];
    const float* q_dw   = (const float*)d_in[10];
    const float* kv_w   = (const float*)d_in[11];
    const float* kv_dw  = (const float*)d_in[12];
    const float* ln_w   = (const float*)d_in[13];
    const float* ln_b   = (const float*)d_in[14];
    const float* po_w   = (const float*)d_in[15];
    const float* po_b   = (const float*)d_in[16];
    float* out = (float*)d_out;

    float* fws = (float*)d_ws;
    float* pooled = fws; fws += 1024;
    float* gates  = fws; fws += 64;
    float* gsum   = fws; fws += 64;
    float* weff   = fws; fws += 4 * 96 * 64;
    float* powf   = fws; fws += 4096;
    float* p1f    = fws; fws += 8192;
    uintptr_t a = ((uintptr_t)fws + 255) & ~(uintptr_t)255;
    float* obuf = (float*)a;                                     // 16*32*HW f32 = 32 MB
    unsigned short* qkvpre = (unsigned short*)(obuf + (size_t)BATCH * 32 * HW);  // 48 MB bf16
    unsigned short* qkvb   = qkvpre + (size_t)BATCH * 96 * HW;                   // 48 MB bf16

    k_pool<<<1024, 256, 0, stream>>>(x, pooled);
    k_gate<<<1, 64, 0, stream>>>(pooled, femb, noise, gate_w, fgw, gates, gsum);
    k_weff<<<96, 256, 0, stream>>>(q_w, kv_w, p0, weff);
    k_xpose<<<32, 256, 0, stream>>>(po_w, p1, powf, p1f);
    k_init<<<16384, 256, 0, stream>>>(x, gsum, out);
    for (int e = 0; e < 4; e++) {
        k_qkvpre<<<768, 256, 0, stream>>>(x, weff, gates, e, qkvpre);
        k_dw3<<<8192, 256, 0, stream>>>(qkvpre, q_dw, gates, e, qkvb);
        k_dw7<<<16384, 256, 0, stream>>>(qkvpre, kv_dw, gates, e, qkvb);
        k_circ<<<BATCH * 2048, 256, 0, stream>>>(qkvb, gates, e, obuf);
        k_tail<<<BATCH * 64, 256, 0, stream>>>(obuf, qkvb, shr, gates, e,
                                               powf, po_b, ln_w, ln_b, p1f, p2, out);
    }
}

// Round 3
// 745.530 us; speedup vs baseline: 1.5876x; 1.5876x over previous
//
#include <hip/hip_runtime.h>
#include <hip/hip_bf16.h>

#define BATCH 16
#define DIM 64
#define RANK 32
#define H 128
#define W 128
#define HW (H*W)
#define NSLOT 32

static __device__ __forceinline__ float bu2f(unsigned short u) {
    return __uint_as_float(((unsigned)u) << 16);
}
static __device__ __forceinline__ unsigned short f2bu(float f) {
    union { __hip_bfloat16 h; unsigned short u; } cv;
    cv.h = __float2bfloat16(f);
    return cv.u;
}
static __device__ __forceinline__ float ulo(unsigned int w) { return __uint_as_float(w << 16); }
static __device__ __forceinline__ float uhi(unsigned int w) { return __uint_as_float(w & 0xffff0000u); }

// ---------------- routing ----------------
__global__ __launch_bounds__(256) void k_pool(const float* __restrict__ x,
                                              float* __restrict__ pooled) {
    int bc = blockIdx.x;  // b*64+c
    const float4* p = (const float4*)(x + (size_t)bc * HW);
    float s = 0.f;
    for (int i = threadIdx.x; i < HW / 4; i += 256) {
        float4 v = p[i];
        s += v.x + v.y + v.z + v.w;
    }
#pragma unroll
    for (int off = 32; off > 0; off >>= 1) s += __shfl_down(s, off);
    __shared__ float red[4];
    if ((threadIdx.x & 63) == 0) red[threadIdx.x >> 6] = s;
    __syncthreads();
    if (threadIdx.x == 0)
        pooled[bc] = (red[0] + red[1] + red[2] + red[3]) * (1.f / HW);
}

// writes slot table: slot s=2b+{0,1} -> (b, e, gate); plus gsum[b]
__global__ __launch_bounds__(64) void k_gate(const float* __restrict__ pooled,
                                             const float* __restrict__ freq_emb,
                                             const float* __restrict__ noise,
                                             const float* __restrict__ gate_w,
                                             const float* __restrict__ fgw,
                                             int* __restrict__ slot_e,
                                             float* __restrict__ slot_g,
                                             float* __restrict__ gsum) {
    int b = threadIdx.x;
    if (b >= BATCH) return;
    float lg[4];
    for (int e = 0; e < 4; e++) {
        float s = 0.f;
        for (int c = 0; c < 64; c++) s += pooled[b * 64 + c] * gate_w[e * 64 + c];
        for (int c = 0; c < 64; c++) s += freq_emb[b * 64 + c] * fgw[e * 64 + c];
        s += noise[b * 4 + e] * 0.25f;  // NOISE_STD = 1/E
        lg[e] = s;
    }
    float m = fmaxf(fmaxf(lg[0], lg[1]), fmaxf(lg[2], lg[3]));
    float sc[4], Z = 0.f;
    for (int e = 0; e < 4; e++) { sc[e] = expf(lg[e] - m); Z += sc[e]; }
    for (int e = 0; e < 4; e++) sc[e] /= Z;
    int i0 = 0;
    for (int e = 1; e < 4; e++) if (sc[e] > sc[i0]) i0 = e;
    int i1 = -1;
    for (int e = 0; e < 4; e++) {
        if (e == i0) continue;
        if (i1 < 0 || sc[e] > sc[i1]) i1 = e;
    }
    slot_e[2 * b] = i0;     slot_g[2 * b] = sc[i0];
    slot_e[2 * b + 1] = i1; slot_g[2 * b + 1] = sc[i1];
    gsum[b] = sc[i0] + sc[i1];
}

// ---------------- weight prep ----------------
// weff[e][c][j] = (j<32 ? q_w[e][j][:] : kv_w[e][j-32][:]) . p0[e][:][c]
__global__ __launch_bounds__(256) void k_weff(const float* __restrict__ q_w,
                                              const float* __restrict__ kv_w,
                                              const float* __restrict__ p0,
                                              float* __restrict__ weff) {
    int t = blockIdx.x * 256 + threadIdx.x;
    if (t >= 4 * 96 * 64) return;
    int c = t & 63;
    int j = (t >> 6) % 96;
    int e = t / (96 * 64);
    const float* p0p = p0 + (size_t)e * RANK * DIM;
    float s = 0.f;
    if (j < 32) {
        const float* qp = q_w + (e * 32 + j) * 32;
        for (int r = 0; r < 32; r++) s += qp[r] * p0p[r * DIM + c];
    } else {
        const float* kp = kv_w + (e * 64 + (j - 32)) * 32;
        for (int r = 0; r < 32; r++) s += kp[r] * p0p[r * DIM + c];
    }
    weff[(e * 64 + c) * 96 + j] = s;
}

// transpose po_w [e][oc][c]->[e][c][oc] and p1 [e][j][c]->[e][c][j]
__global__ __launch_bounds__(256) void k_xpose(const float* __restrict__ po_w,
                                               const float* __restrict__ p1,
                                               float* __restrict__ powf,
                                               float* __restrict__ p1f) {
    int t = blockIdx.x * 256 + threadIdx.x;  // 8192
    if (t < 4096) {
        int e = t >> 10, oc = (t >> 5) & 31, c = t & 31;
        powf[(e * 32 + c) * 32 + oc] = po_w[t];
    }
    int e = t >> 11, j = (t >> 6) & 31, c = t & 63;
    p1f[(e * 64 + c) * 32 + j] = p1[t];
}

// ---------------- slot pipeline ----------------
// conv1x1: qkvpre[slot][j][p] = sum_c weff[e][c][j] * x[b][c][p]
__global__ __launch_bounds__(256) void k_qkvpre(const float* __restrict__ x,
                                                const float* __restrict__ weff,
                                                const int* __restrict__ slot_e,
                                                unsigned short* __restrict__ qkvpre) {
    int t = blockIdx.x;               // slot*48 + tile*3 + jg
    int jg = t % 3;
    int tile = (t / 3) & 15;
    int slot = t / 48;
    int b = slot >> 1;
    int e = slot_e[slot];
    const float* wp = weff + e * 96 * 64 + jg * 32;
    int p0 = tile * 1024 + threadIdx.x * 4;
    const float* xb = x + (size_t)b * DIM * HW + p0;
    float a0[32], a1[32], a2[32], a3[32];
#pragma unroll
    for (int j = 0; j < 32; j++) { a0[j] = 0.f; a1[j] = 0.f; a2[j] = 0.f; a3[j] = 0.f; }
    for (int c = 0; c < DIM; c++) {
        float4 xv = *(const float4*)(xb + (size_t)c * HW);
        const float* wr = wp + c * 96;
#pragma unroll
        for (int j = 0; j < 32; j++) {
            float wv = wr[j];
            a0[j] += wv * xv.x; a1[j] += wv * xv.y; a2[j] += wv * xv.z; a3[j] += wv * xv.w;
        }
    }
    unsigned short* op = qkvpre + ((size_t)slot * 96 + jg * 32) * HW + p0;
#pragma unroll
    for (int j = 0; j < 32; j++) {
        ushort4 o4;
        o4.x = f2bu(a0[j]); o4.y = f2bu(a1[j]); o4.z = f2bu(a2[j]); o4.w = f2bu(a3[j]);
        *(ushort4*)(op + (size_t)j * HW) = o4;
    }
}

// fused depthwise: ch 0..31 -> 3x3 pad1 (q_dw), ch 32..95 -> 7x7 pad3 (kv_dw)
__global__ __launch_bounds__(256) void k_dw(const unsigned short* __restrict__ qkvpre,
                                            const float* __restrict__ q_dw,
                                            const float* __restrict__ kv_dw,
                                            const int* __restrict__ slot_e,
                                            unsigned short* __restrict__ qkv) {
    int t = blockIdx.x;               // slot*(96*16) + c*16 + tile
    int tile = t & 15;
    int c = (t >> 4) % 96;
    int slot = t / (96 * 16);
    int e = slot_e[slot];
    int tx = (threadIdx.x & 31) * 4;
    int ty = threadIdx.x >> 5;
    int y = tile * 8 + ty;
    const unsigned short* in = qkvpre + ((size_t)slot * 96 + c) * HW;
    float s0 = 0.f, s1 = 0.f, s2 = 0.f, s3 = 0.f;
    if (c < 32) {
        const float* wp = q_dw + (e * 32 + c) * 9;
#pragma unroll
        for (int ky = 0; ky < 3; ky++) {
            int yy = y + ky - 1;
            if (yy < 0 || yy >= H) continue;
            const unsigned short* row = in + yy * W;
            float r[6];
#pragma unroll
            for (int d = 0; d < 6; d++) {
                int xx = tx + d - 1;
                r[d] = (xx >= 0 && xx < W) ? bu2f(row[xx]) : 0.f;
            }
#pragma unroll
            for (int kx = 0; kx < 3; kx++) {
                float wv = wp[ky * 3 + kx];
                s0 += wv * r[kx]; s1 += wv * r[kx + 1]; s2 += wv * r[kx + 2]; s3 += wv * r[kx + 3];
            }
        }
    } else {
        const float* wp = kv_dw + (e * 64 + (c - 32)) * 49;
#pragma unroll
        for (int ky = 0; ky < 7; ky++) {
            int yy = y + ky - 3;
            if (yy < 0 || yy >= H) continue;
            const unsigned short* row = in + yy * W;
            float r[10];
#pragma unroll
            for (int d = 0; d < 10; d++) {
                int xx = tx + d - 3;
                r[d] = (xx >= 0 && xx < W) ? bu2f(row[xx]) : 0.f;
            }
#pragma unroll
            for (int kx = 0; kx < 7; kx++) {
                float wv = wp[ky * 7 + kx];
                s0 += wv * r[kx]; s1 += wv * r[kx + 1]; s2 += wv * r[kx + 2]; s3 += wv * r[kx + 3];
            }
        }
    }
    ushort4 o4; o4.x = f2bu(s0); o4.y = f2bu(s1); o4.z = f2bu(s2); o4.w = f2bu(s3);
    *(ushort4*)(qkv + ((size_t)slot * 96 + c) * HW + y * W + tx) = o4;
}

// per-8x8-patch circular conv, FMA-bound form:
// o[i][j] = sum_mi sum_dj q[mi][(j-dj)&7] * k[(i-mi)&7][dj]
// lane = (unit, row i), computes full 8-px output row; k quad reads are aligned b128.
__global__ __launch_bounds__(256) void k_circ(const unsigned short* __restrict__ qkv,
                                              unsigned short* __restrict__ obuf) {
    __shared__ float Qs[32][68];
    __shared__ float Kp[32][68];
    int u = threadIdx.x >> 3;      // 0..31 block-local unit
    int i = threadIdx.x & 7;       // row
    int U = blockIdx.x * 32 + u;   // unit = (slot, c, patch)
    int patch = U & 255;
    int c = (U >> 8) & 31;
    int slot = U >> 13;
    int py = patch >> 4, px = patch & 15;
    size_t rowbase = ((size_t)slot * 96 + c) * HW + (py * 8 + i) * W + px * 8;
    uint4 qu = *(const uint4*)(qkv + rowbase);
    uint4 ku = *(const uint4*)(qkv + rowbase + (size_t)32 * HW);
    float qr[8], kr[8];
    qr[0] = ulo(qu.x); qr[1] = uhi(qu.x); qr[2] = ulo(qu.y); qr[3] = uhi(qu.y);
    qr[4] = ulo(qu.z); qr[5] = uhi(qu.z); qr[6] = ulo(qu.w); qr[7] = uhi(qu.w);
    kr[0] = ulo(ku.x); kr[1] = uhi(ku.x); kr[2] = ulo(ku.y); kr[3] = uhi(ku.y);
    kr[4] = ulo(ku.z); kr[5] = uhi(ku.z); kr[6] = ulo(ku.w); kr[7] = uhi(ku.w);
    *(float4*)&Qs[u][i * 8] = *(float4*)&qr[0];
    *(float4*)&Qs[u][i * 8 + 4] = *(float4*)&qr[4];
    *(float4*)&Kp[u][i * 8] = *(float4*)&kr[0];
    *(float4*)&Kp[u][i * 8 + 4] = *(float4*)&kr[4];
    __syncthreads();
    float acc[8];
#pragma unroll
    for (int j = 0; j < 8; j++) acc[j] = 0.f;
#pragma unroll
    for (int mi = 0; mi < 8; mi++) {
        int r = (i - mi) & 7;
        float qv[8], ka[4], kb[4];
        *(float4*)&qv[0] = *(const float4*)&Qs[u][mi * 8];
        *(float4*)&qv[4] = *(const float4*)&Qs[u][mi * 8 + 4];
        *(float4*)&ka[0] = *(const float4*)&Kp[u][r * 8];
        *(float4*)&kb[0] = *(const float4*)&Kp[u][r * 8 + 4];
#pragma unroll
        for (int j = 0; j < 8; j++) {
            float s = acc[j];
#pragma unroll
            for (int t = 0; t < 4; t++) {
                s += ka[t] * qv[(j - t) & 7];
                s += kb[t] * qv[(j - 4 - t) & 7];
            }
            acc[j] = s;
        }
    }
    size_t obase = ((size_t)slot * 32 + c) * HW + (py * 8 + i) * W + px * 8;
    uint4 ov;
    ov.x = (unsigned)f2bu(acc[0]) | ((unsigned)f2bu(acc[1]) << 16);
    ov.y = (unsigned)f2bu(acc[2]) | ((unsigned)f2bu(acc[3]) << 16);
    ov.z = (unsigned)f2bu(acc[4]) | ((unsigned)f2bu(acc[5]) << 16);
    ov.w = (unsigned)f2bu(acc[6]) | ((unsigned)f2bu(acc[7]) << 16);
    *(uint4*)(obuf + obase) = ov;
}

// per-image fused tail: for both slots of image b:
// LN(obuf) -> *v -> po -> *silu(p1@shared) -> p2 -> combine with gsum*x -> out
__global__ __launch_bounds__(256) void k_tail(const unsigned short* __restrict__ obuf,
                                              const unsigned short* __restrict__ qkv,
                                              const float* __restrict__ shr,
                                              const float* __restrict__ x,
                                              const int* __restrict__ slot_e,
                                              const float* __restrict__ slot_g,
                                              const float* __restrict__ gsum,
                                              const float* __restrict__ powf,
                                              const float* __restrict__ po_b,
                                              const float* __restrict__ ln_w,
                                              const float* __restrict__ ln_b,
                                              const float* __restrict__ p1f,
                                              const float* __restrict__ p2,
                                              float* __restrict__ out) {
    int b = blockIdx.x >> 6;
    int p = ((blockIdx.x & 63) << 8) + threadIdx.x;
    float att[2][32];
    int eidx[2];
    float gv[2];
#pragma unroll
    for (int si = 0; si < 2; si++) {
        int slot = 2 * b + si;
        int e = slot_e[slot];
        eidx[si] = e;
        gv[si] = slot_g[slot];
        const unsigned short* op = obuf + (size_t)slot * 32 * HW + p;
        float o[32];
#pragma unroll
        for (int c = 0; c < 32; c++) o[c] = bu2f(op[(size_t)c * HW]);
        float mu = 0.f;
#pragma unroll
        for (int c = 0; c < 32; c++) mu += o[c];
        mu *= (1.f / 32.f);
        float var = 0.f;
#pragma unroll
        for (int c = 0; c < 32; c++) { float d = o[c] - mu; var += d * d; }
        float rinv = rsqrtf(var * (1.f / 32.f) + 1e-5f);
        const float* powp = powf + e * 1024;
        const float* lnwp = ln_w + e * 32;
        const float* lnbp = ln_b + e * 32;
        const float* pobp = po_b + e * 32;
        const unsigned short* vp = qkv + ((size_t)slot * 96 + 64) * HW + p;
#pragma unroll
        for (int j = 0; j < 32; j++) att[si][j] = pobp[j];
        for (int c = 0; c < 32; c++) {
            float uu = ((o[c] - mu) * rinv * lnwp[c] + lnbp[c]) * bu2f(vp[(size_t)c * HW]);
            const float* pr = powp + c * 32;
#pragma unroll
            for (int j = 0; j < 32; j++) att[si][j] += pr[j] * uu;
        }
        float t[32];
#pragma unroll
        for (int j = 0; j < 32; j++) t[j] = 0.f;
        const float* shp = shr + (size_t)b * 64 * HW + p;
        const float* p1p = p1f + e * 2048;
        for (int c = 0; c < 64; c++) {
            float sv = shp[(size_t)c * HW];
            const float* pr = p1p + c * 32;
#pragma unroll
            for (int j = 0; j < 32; j++) t[j] += pr[j] * sv;
        }
#pragma unroll
        for (int j = 0; j < 32; j++) {
            float tv = t[j];
            att[si][j] *= tv * __builtin_amdgcn_rcpf(1.f + __expf(-tv));
        }
    }
    float gs = gsum[b];
    const float* xp = x + (size_t)b * 64 * HW + p;
    float* oa = out + (size_t)b * 64 * HW + p;
    const float* p2a = p2 + eidx[0] * 2048;
    const float* p2b = p2 + eidx[1] * 2048;
    float g0 = gv[0], g1 = gv[1];
    for (int oc = 0; oc < 64; oc++) {
        const float* pa = p2a + oc * 32;
        const float* pb = p2b + oc * 32;
        float sa = 0.f, sb = 0.f;
#pragma unroll
        for (int j = 0; j < 32; j++) {
            sa += pa[j] * att[0][j];
            sb += pb[j] * att[1][j];
        }
        oa[(size_t)oc * HW] = g0 * sa + g1 * sb + gs * xp[(size_t)oc * HW];
    }
}

extern "C" void kernel_launch(void* const* d_in, const int* in_sizes, int n_in,
                              void* d_out, int out_size, void* d_ws, size_t ws_size,
                              hipStream_t stream) {
    (void)in_sizes; (void)n_in; (void)out_size; (void)ws_size;
    const float* x      = (const float*)d_in[0];
    const float* shr    = (const float*)d_in[1];
    const float* femb   = (const float*)d_in[2];
    const float* noise  = (const float*)d_in[3];
    const float* gate_w = (const float*)d_in[4];
    const float* fgw    = (const float*)d_in[5];
    const float* p0     = (const float*)d_in[6];
    const float* p1     = (const float*)d_in[7];
    const float* p2     = (const float*)d_in[8];
    const float* q_w    = (const float*)d_in[9];
    const float* q_dw   = (const float*)d_in[10];
    const float* kv_w   = (const float*)d_in[11];
    const float* kv_dw  = (const float*)d_in[12];
    const float* ln_w   = (const float*)d_in[13];
    const float* ln_b   = (const float*)d_in[14];
    const float* po_w   = (const float*)d_in[15];
    const float* po_b   = (const float*)d_in[16];
    float* out = (float*)d_out;

    float* fws = (float*)d_ws;
    float* pooled = fws; fws += 1024;
    float* gsum   = fws; fws += 16;
    float* slot_g = fws; fws += 32;
    int*   slot_e = (int*)fws; fws += 32;
    float* weff   = fws; fws += 4 * 96 * 64;
    float* powf   = fws; fws += 4096;
    float* p1f    = fws; fws += 8192;
    uintptr_t a = ((uintptr_t)fws + 255) & ~(uintptr_t)255;
    unsigned short* qkvpre = (unsigned short*)a;                      // 32*96*HW bf16 = 100.7 MB
    unsigned short* qkvb   = qkvpre + (size_t)NSLOT * 96 * HW;        // 100.7 MB
    unsigned short* obuf   = qkvb + (size_t)NSLOT * 96 * HW;          // 32*32*HW bf16 = 33.6 MB

    k_pool<<<1024, 256, 0, stream>>>(x, pooled);
    k_gate<<<1, 64, 0, stream>>>(pooled, femb, noise, gate_w, fgw, slot_e, slot_g, gsum);
    k_weff<<<96, 256, 0, stream>>>(q_w, kv_w, p0, weff);
    k_xpose<<<32, 256, 0, stream>>>(po_w, p1, powf, p1f);
    k_qkvpre<<<NSLOT * 48, 256, 0, stream>>>(x, weff, slot_e, qkvpre);
    k_dw<<<NSLOT * 96 * 16, 256, 0, stream>>>(qkvpre, q_dw, kv_dw, slot_e, qkvb);
    k_circ<<<NSLOT * 32 * 256 / 32, 256, 0, stream>>>(qkvb, obuf);
    k_tail<<<BATCH * 64, 256, 0, stream>>>(obuf, qkvb, shr, x, slot_e, slot_g, gsum,
                                           powf, po_b, ln_w, ln_b, p1f, p2, out);
}